// Round 7
// baseline (110.928 us; speedup 1.0000x reference)
//
#include <hip/hip_runtime.h>

// Implicit-GEMM conv2d via bf16 MFMA (32x32x16), ws pre-pack.
// GEMM: M=256=Cout, N=123008, K=1152 (k = tap*128+ci).
// Block tile 256x128, BK=32, 256 thr / 4 waves (2Mx2N), wave tile 128x64
// (acc = 4x2 of 32x32 = 128 VGPR). LDS: 3 x 24KB triple buffer -> 2 blocks/CU.
// Depth-2 prefetch, counted vmcnt(6); one raw s_barrier per K-step.
// LDS layout: paired rows -> 128B lines; line L holds rows {2L,2L+1};
// slotpos = (row&1)*4 + (g ^ (L&3)), g = global 8-elem k-slot. Conflict-free
// b128 reads (each 8-lane group covers all 32 banks); staged linearly by
// global_load_lds with the inverse swizzle applied to the global source.
//   A' [256][1152] bf16   (from w [256][128][3][3] f32)
//   xp [32][64][64][128] bf16 (NHWC, from x [32][128][64][64] f32)

using bf16x8 = __attribute__((ext_vector_type(8))) __bf16;
using f32x4  = __attribute__((ext_vector_type(4))) float;
using f32x16 = __attribute__((ext_vector_type(16))) float;

constexpr int CIN  = 128;
constexpr int HW   = 64;
constexpr int COUT = 256;
constexpr int OW   = 62;
constexpr int NS   = 62 * 62;          // 3844
constexpr int NTOT = 32 * NS;          // 123008
constexpr int KTOT = 9 * CIN;          // 1152
constexpr int BN = 128, BK = 32;
constexpr int NSTEP = KTOT / BK;       // 36
constexpr int NWG = NTOT / BN;         // 961

constexpr size_t AP_BYTES = (size_t)COUT * KTOT * 2;            // 589824
constexpr size_t XP_BYTES = (size_t)32 * HW * HW * CIN * 2;     // 33554432
constexpr size_t WS_NEEDED = AP_BYTES + XP_BYTES;

constexpr int SBUF = 24576;            // per K-step buffer: A 16KB + B 8KB
constexpr int BOFF = 16384;            // B offset inside buffer

__device__ __forceinline__ unsigned short f2bf(float f) {
  unsigned u = __float_as_uint(f);
  u += 0x7fffu + ((u >> 16) & 1u);     // RNE
  return (unsigned short)(u >> 16);
}
__device__ __forceinline__ unsigned pack2(float a, float b) {
  return (unsigned)f2bf(a) | ((unsigned)f2bf(b) << 16);
}

__device__ __forceinline__ void gld16(const void* g, void* l) {
  __builtin_amdgcn_global_load_lds(
      (const __attribute__((address_space(1))) unsigned int*)g,
      (__attribute__((address_space(3))) unsigned int*)l, 16, 0, 0);
}

// ---------------- prepack kernels ----------------

__global__ __launch_bounds__(256)
void prepack_w(const float* __restrict__ w, unsigned* __restrict__ ap32) {
  const int idx = blockIdx.x * 256 + threadIdx.x;     // 0..147455
  const int co  = idx / 576;
  const int k2  = idx - co * 576;
  const int k   = k2 * 2;
  const int tap = k >> 7;
  const int ci  = k & 127;
  const float v0 = w[(co * 128 + ci) * 9 + tap];
  const float v1 = w[(co * 128 + ci + 1) * 9 + tap];
  ap32[idx] = pack2(v0, v1);
}

__global__ __launch_bounds__(256)
void prepack_x(const float* __restrict__ x, unsigned* __restrict__ xp32) {
  const int bh = blockIdx.x;           // b*64 + h
  const int b  = bh >> 6, h = bh & 63;
  const int t  = threadIdx.x;
  const int c  = t & 63;               // ci-pair index (ci = 2c, 2c+1)
  const int w0 = (t >> 6) * 16;

  const float* p0 = x + (((size_t)(b * 128 + 2 * c) * HW) + h) * HW + w0;
  const float* p1 = p0 + (size_t)HW * HW;
  float r0[16], r1[16];
#pragma unroll
  for (int j = 0; j < 4; ++j) {
    *reinterpret_cast<float4*>(&r0[j * 4]) = reinterpret_cast<const float4*>(p0)[j];
    *reinterpret_cast<float4*>(&r1[j * 4]) = reinterpret_cast<const float4*>(p1)[j];
  }
  unsigned* o = xp32 + ((size_t)bh * HW + w0) * 64 + c;
#pragma unroll
  for (int j = 0; j < 16; ++j)
    o[j * 64] = pack2(r0[j], r1[j]);
}

// ---------------- main kernel ----------------

__global__ __launch_bounds__(256, 2)
void conv_main(const unsigned short* __restrict__ Ap,
               const unsigned short* __restrict__ Xp,
               float* __restrict__ out) {
  __shared__ __align__(16) char lds[3 * SBUF];   // 72 KiB -> 2 blocks/CU

  const int tid  = threadIdx.x;
  const int lane = tid & 63;
  const int wid  = tid >> 6;       // 0..3
  const int wm   = wid >> 1;       // M half: co rows wm*128..+127
  const int wn   = wid & 1;        // N half: cols wn*64..+63

  // ---- bijective XCD swizzle over 961 n-panels ----
  int wg;
  {
    const int f = blockIdx.x;
    constexpr int q = NWG / 8, r = NWG % 8;    // 120, 1
    const int xc = f & 7, p = f >> 3;
    wg = (xc < r ? xc * (q + 1) : r * (q + 1) + (xc - r) * q) + p;
  }
  const int n_base = wg * BN;

  // ---- staging decode (per lane): within an 8-line (1KB) chunk ----
  const int lrow2 = ((lane >> 3) << 1) + ((lane >> 2) & 1);   // row within 16
  const int g8    = ((lane & 3) ^ ((lane >> 3) & 3)) * 8;     // global k-slot*8
  // A: chunk ch = wid*4+q covers rows ch*16..+15
  int aoff[4];
#pragma unroll
  for (int q = 0; q < 4; ++q) {
    const int row = (wid * 4 + q) * 16 + lrow2;               // co 0..255
    aoff[q] = row * KTOT + g8;
  }
  // B: chunk chb = wid*2+q covers n-rows chb*16..+15
  unsigned xoff[2];
#pragma unroll
  for (int q = 0; q < 2; ++q) {
    const int rn = (wid * 2 + q) * 16 + lrow2;                // 0..127
    const unsigned n  = n_base + rn;                          // < NTOT (no tail)
    const unsigned bi = n / NS;
    const unsigned s0 = n - bi * NS;
    const unsigned oh = s0 / OW;
    const unsigned ww = s0 - oh * OW;
    xoff[q] = ((bi * HW + oh) * HW + ww) * CIN + g8;
  }

  // ---- fragment read addressing ----
  const int cl = lane & 31;
  const int gl = lane >> 5;
  const int q4 = (cl >> 1) & 3;
  const int sw0 = ((gl)     ^ q4) * 16;   // kf=0 slot byte offset
  const int sw1 = ((2 + gl) ^ q4) * 16;   // kf=1
  const int ABASE = ((wm * 64 + (cl >> 1)) * 128) + (cl & 1) * 64;
  const int BBASE = BOFF + ((wn * 32 + (cl >> 1)) * 128) + (cl & 1) * 64;

  f32x16 acc[4][2] = {};

  auto STAGE = [&](int t, char* dst) {
    const int tap = t >> 2;
    const int kh  = tap / 3;
    const int kw  = tap - kh * 3;
    const int ak  = t * BK;                              // A k-linear
    const int xk  = (kh * HW + kw) * CIN + (t & 3) * BK; // B
#pragma unroll
    for (int q = 0; q < 4; ++q)
      gld16(Ap + aoff[q] + ak, dst + (wid * 4 + q) * 1024);
#pragma unroll
    for (int q = 0; q < 2; ++q)
      gld16(Xp + xoff[q] + xk, dst + BOFF + (wid * 2 + q) * 1024);
  };

  STAGE(0, lds);
  STAGE(1, lds + SBUF);

#pragma unroll
  for (int t = 0; t < NSTEP; ++t) {
    const char* cur = lds + (t % 3) * SBUF;
    if (t < NSTEP - 1) asm volatile("s_waitcnt vmcnt(6)" ::: "memory");
    else               asm volatile("s_waitcnt vmcnt(0)" ::: "memory");
    __builtin_amdgcn_s_barrier();
    __builtin_amdgcn_sched_barrier(0);
    if (t + 2 < NSTEP) STAGE(t + 2, lds + ((t + 2) % 3) * SBUF);

#pragma unroll
    for (int kf = 0; kf < 2; ++kf) {
      const int sw = kf ? sw1 : sw0;
      bf16x8 a[4], b[2];
#pragma unroll
      for (int mt = 0; mt < 4; ++mt)
        a[mt] = *reinterpret_cast<const bf16x8*>(cur + ABASE + mt * 2048 + sw);
#pragma unroll
      for (int nt = 0; nt < 2; ++nt)
        b[nt] = *reinterpret_cast<const bf16x8*>(cur + BBASE + nt * 2048 + sw);

      __builtin_amdgcn_s_setprio(1);
#pragma unroll
      for (int mt = 0; mt < 4; ++mt)
#pragma unroll
        for (int nt = 0; nt < 2; ++nt)
          acc[mt][nt] = __builtin_amdgcn_mfma_f32_32x32x16_bf16(
              a[mt], b[nt], acc[mt][nt], 0, 0, 0);
      __builtin_amdgcn_s_setprio(0);
    }
  }

  // ---- epilogue: 32x32 C/D layout col=lane&31, row=(r&3)+8*(r>>2)+4*gl ----
#pragma unroll
  for (int mt = 0; mt < 4; ++mt)
#pragma unroll
    for (int nt = 0; nt < 2; ++nt) {
      const unsigned n  = n_base + wn * 64 + nt * 32 + cl;
      const unsigned b2 = n / NS;
      const unsigned s2 = n - b2 * NS;
      float* op = out + (size_t)b2 * (COUT * NS) + s2
                      + (size_t)(wm * 128 + mt * 32 + gl * 4) * NS;
#pragma unroll
      for (int r = 0; r < 16; ++r)
        op[((r & 3) + 8 * (r >> 2)) * NS] = acc[mt][nt][r];
    }
}

// ---------------- fallback (no-ws path, round-1 proven) ----------------

__global__ __launch_bounds__(256)
void conv_fallback(const float* __restrict__ x, const float* __restrict__ w,
                   float* __restrict__ out) {
  __shared__ __align__(16) unsigned short As[128 * 32];
  __shared__ __align__(16) unsigned short Bs[128 * 32];

  const int t    = threadIdx.x;
  const int lane = t & 63;
  const int wid  = t >> 6;
  const int wm   = wid >> 1;
  const int wn   = wid & 1;
  const int co_base = blockIdx.x * 128;
  const int n_base  = blockIdx.y * 128;

  const int bn  = t & 127;
  const int bg0 = t >> 7;
  const unsigned n0   = n_base + bn;
  const unsigned bidx = n0 / NS;
  const unsigned s0   = n0 - bidx * NS;
  const unsigned oh   = s0 / OW;
  const unsigned ow   = s0 - oh * OW;
  const float* xb = x + (bidx * (CIN * HW * HW) + oh * HW + ow);

  const int am  = t & 127;
  const int ag0 = (t >> 7) * 2;
  const float* wb = w + (co_base + am) * KTOT;

  f32x4 acc[4][4] = {};

  for (int ks = 0; ks < 36; ++ks) {
    const int tap = ks >> 2;
    const int ci0 = (ks & 3) * 32;
    const int kh  = tap / 3;
    const int kw  = tap - kh * 3;
    const int xo  = kh * HW + kw;

    float av[2][8], bv[2][8];
#pragma unroll
    for (int gi = 0; gi < 2; ++gi) {
      const int g = ag0 + gi;
#pragma unroll
      for (int j = 0; j < 8; ++j)
        av[gi][j] = wb[(ci0 + g * 8 + j) * 9 + tap];
    }
#pragma unroll
    for (int gi = 0; gi < 2; ++gi) {
      const int g = bg0 + gi * 2;
#pragma unroll
      for (int j = 0; j < 8; ++j)
        bv[gi][j] = xb[xo + (ci0 + g * 8 + j) * (HW * HW)];
    }

    __syncthreads();

#pragma unroll
    for (int gi = 0; gi < 2; ++gi) {
      const int g = ag0 + gi;
      uint4 pv;
      pv.x = pack2(av[gi][0], av[gi][1]);
      pv.y = pack2(av[gi][2], av[gi][3]);
      pv.z = pack2(av[gi][4], av[gi][5]);
      pv.w = pack2(av[gi][6], av[gi][7]);
      *reinterpret_cast<uint4*>(&As[am * 32 + ((g ^ ((am >> 1) & 3)) << 3)]) = pv;
    }
#pragma unroll
    for (int gi = 0; gi < 2; ++gi) {
      const int g = bg0 + gi * 2;
      uint4 pv;
      pv.x = pack2(bv[gi][0], bv[gi][1]);
      pv.y = pack2(bv[gi][2], bv[gi][3]);
      pv.z = pack2(bv[gi][4], bv[gi][5]);
      pv.w = pack2(bv[gi][6], bv[gi][7]);
      *reinterpret_cast<uint4*>(&Bs[bn * 32 + ((g ^ ((bn >> 1) & 3)) << 3)]) = pv;
    }

    __syncthreads();

    bf16x8 af[4], bfr[4];
    const int g = lane >> 4;
#pragma unroll
    for (int mi = 0; mi < 4; ++mi) {
      const int m = wm * 64 + mi * 16 + (lane & 15);
      af[mi] = *reinterpret_cast<const bf16x8*>(&As[m * 32 + ((g ^ ((m >> 1) & 3)) << 3)]);
    }
#pragma unroll
    for (int ni = 0; ni < 4; ++ni) {
      const int nn = wn * 64 + ni * 16 + (lane & 15);
      bfr[ni] = *reinterpret_cast<const bf16x8*>(&Bs[nn * 32 + ((g ^ ((nn >> 1) & 3)) << 3)]);
    }
#pragma unroll
    for (int mi = 0; mi < 4; ++mi)
#pragma unroll
      for (int ni = 0; ni < 4; ++ni)
        acc[mi][ni] = __builtin_amdgcn_mfma_f32_16x16x32_bf16(af[mi], bfr[ni],
                                                              acc[mi][ni], 0, 0, 0);
  }

#pragma unroll
  for (int ni = 0; ni < 4; ++ni) {
    const unsigned n  = n_base + wn * 64 + ni * 16 + (lane & 15);
    const unsigned b2 = n / NS;
    const unsigned s2 = n - b2 * NS;
    float* op = out + (size_t)b2 * (COUT * NS) + s2
                    + (size_t)(co_base + wm * 64 + (lane >> 4) * 4) * NS;
#pragma unroll
    for (int mi = 0; mi < 4; ++mi)
#pragma unroll
      for (int r = 0; r < 4; ++r)
        op[(mi * 16 + r) * NS] = acc[mi][ni][r];
  }
}

extern "C" void kernel_launch(void* const* d_in, const int* in_sizes, int n_in,
                              void* d_out, int out_size, void* d_ws, size_t ws_size,
                              hipStream_t stream) {
  const float* x = (const float*)d_in[0];   // [32,128,64,64]
  const float* w = (const float*)d_in[1];   // [256,128,3,3]
  float* out = (float*)d_out;               // [32,256,62,62]

  if (ws_size >= WS_NEEDED) {
    unsigned* ap32 = (unsigned*)d_ws;
    unsigned short* Ap = (unsigned short*)d_ws;
    unsigned short* Xp = (unsigned short*)((char*)d_ws + AP_BYTES);
    unsigned* xp32 = (unsigned*)Xp;
    prepack_w<<<576, 256, 0, stream>>>(w, ap32);
    prepack_x<<<32 * HW, 256, 0, stream>>>(x, xp32);
    conv_main<<<dim3(NWG), 256, 0, stream>>>(Ap, Xp, out);
  } else {
    conv_fallback<<<dim3(2, NTOT / 128), 256, 0, stream>>>(x, w, out);
  }
}